// Round 17
// baseline (218.942 us; speedup 1.0000x reference)
//
#include <hip/hip_runtime.h>
#include <math.h>

#define TT 4096
#define DD 1024
#define HH 768
#define NE 23
#define NG 24          // 23 experts + shared as group 23
#define BM 128
#define BN 128
#define BK 64
#define MAXT 160       // sum ceil(n_e/128) <= 119, + 32 shared tiles = 151
#define KB1 16         // DD/64
#define KB2 12         // HH/64
#define NY1 6          // HH/BN
#define NY2 8          // DD/BN
#define NWG1 (MAXT*NY1)   // 960  (div by 8)
#define NWG2 (MAXT*NY2)   // 1280 (div by 8)
#define GATE_BLKS 512     // 8 tokens per block
#define CVT1_BLKS 1152    // W1: 12 nblk * 4 kquad * 24 e
#define CVT_TOT   2304    // + W2: 16 nblk * 3 kquad * 24 e

// ws word offsets (misc, < 512KB)
#define WS_CURS   0        // 23*16 ints (1 cache line per expert)
#define WS_OFFS   576
#define WS_TOTAL  640
#define WS_T2E    672      // tile -> expert/group
#define WS_T2A    832      // tile -> a0
#define WS_TOKE   1024
#define WS_TOKW   13312
#define WS_LTOK   25600
#define WS_LW     41984
#define WS_PPART  58368    // 23*1024 floats (only [0,512) used per expert)
#define WS_CPART  81920    // 23*1024 ints
#define WS_SIDX   106496   // 12288 ints (ends 118784 < 131072)
// ws byte offsets (big buffers)
#define XB_OFF  ((size_t)524288)      // xb bf16: 4096*1024*2  = 8388608
#define H_OFF   ((size_t)8912896)     // H bf16
#define W1B_OFF ((size_t)34078720)    // W1 blocked bf16 (reused after mm1 as yslot)
#define W2B_OFF ((size_t)71827456)    // W2 blocked bf16

typedef short bf16x8 __attribute__((ext_vector_type(8)));
typedef float f32x4 __attribute__((ext_vector_type(4)));

#define S_BARRIER() asm volatile("s_barrier" ::: "memory")
#define WAIT_VM0()  asm volatile("s_waitcnt vmcnt(0)" ::: "memory")

__device__ inline unsigned short bfr(float f) {   // f32 -> bf16 RNE
    unsigned u = __float_as_uint(f);
    u += 0x7fffu + ((u >> 16) & 1u);
    return (unsigned short)(u >> 16);
}
__device__ inline unsigned bfr2(float lo, float hi) {  // pack 2 bf16 into dword
    return (unsigned)bfr(lo) | ((unsigned)bfr(hi) << 16);
}
__device__ inline float b2f(unsigned short u) {
    return __uint_as_float((unsigned)u << 16);
}

__device__ __forceinline__ void gl_lds16(const void* g, void* l) {
    __builtin_amdgcn_global_load_lds(
        (const __attribute__((address_space(1))) unsigned int*)g,
        (__attribute__((address_space(3))) unsigned int*)l, 16, 0, 0);
}

// Exact-f32 gate, LDS-resident gW. 8 tokens/block, all 64 lanes active:
// lane (t, s) accumulates dims d = j*32+s; shuffle-tree reduce; serial top-3
// identical to previous rounds. Also emits xb (bf16 x copy).
__global__ __launch_bounds__(256) void k_gate(
    const float* __restrict__ x, const float* __restrict__ gW,
    const float* __restrict__ gb, const float* __restrict__ bias,
    int* __restrict__ tokE, float* __restrict__ tokW,
    float* __restrict__ Ppart, int* __restrict__ Cpart,
    unsigned short* __restrict__ xb)
{
    __shared__ float gwp[DD * 28];    // 112 KB: [d][28], e in [0,23)
    __shared__ float xs[8 * DD];      // 32 KB
    __shared__ float gvv[8][24];
    __shared__ float ginv[8];
    __shared__ int   sel[8][3];
    const int tid = threadIdx.x;
    const int t0 = blockIdx.x * 8;

    {   // stage 8 token rows of x (coalesced) + write bf16 copy
        const float4* sx = (const float4*)(x + (size_t)t0 * DD);
        float4* dx = (float4*)xs;
        unsigned short* xd = xb + (size_t)t0 * DD;
        #pragma unroll
        for (int c = 0; c < 8; c++) {
            int idx = c * 256 + tid;
            float4 v = sx[idx];
            dx[idx] = v;
            ushort4 u = make_ushort4(bfr(v.x), bfr(v.y), bfr(v.z), bfr(v.w));
            *(ushort4*)(xd + idx * 4) = u;
        }
    }
    for (int i = tid; i < DD * NE; i += 256) {   // stage gW -> [d][28]
        int d = i / NE;
        int e = i - d * NE;
        gwp[d * 28 + e] = gW[i];
    }
    __syncthreads();

    const int t = tid >> 5, s = tid & 31;
    float acc[24];
    #pragma unroll
    for (int e = 0; e < 24; e++) acc[e] = 0.f;
    const float* xrow = xs + t * DD;
    #pragma unroll 2
    for (int j = 0; j < 32; j++) {
        int d = j * 32 + s;
        float xv = xrow[d];                    // bank = s: conflict-free
        const float* gr = gwp + d * 28;
        float g[24];
        #pragma unroll
        for (int q = 0; q < 6; q++) {          // 4-way bank conflict (1.58x) - ok
            float4 v = *(const float4*)(gr + q * 4);
            g[4*q] = v.x; g[4*q+1] = v.y; g[4*q+2] = v.z; g[4*q+3] = v.w;
        }
        #pragma unroll
        for (int e = 0; e < 24; e++) acc[e] = fmaf(xv, g[e], acc[e]);
    }
    #pragma unroll
    for (int e = 0; e < 23; e++) {             // reduce over the 32 s-lanes
        #pragma unroll
        for (int off = 16; off >= 1; off >>= 1)
            acc[e] += __shfl_xor(acc[e], off, 32);
    }
    __syncthreads();
    if (s == 0) {
        float sg[23]; float gsum = 0.f;
        #pragma unroll
        for (int e = 0; e < 23; e++) {
            float sv = 1.f / (1.f + expf(-(acc[e] + gb[e])));
            sg[e] = sv; gvv[t][e] = sv; gsum += sv;
        }
        unsigned chosen = 0; int be[3]; float bw[3];
        #pragma unroll
        for (int k = 0; k < 3; k++) {
            float m = -1e30f; int mi = 0;
            for (int e = 0; e < 23; e++) {
                float kv = sg[e] + bias[e];
                if (!((chosen >> e) & 1u) && kv > m) { m = kv; mi = e; }
            }
            chosen |= 1u << mi; be[k] = mi; bw[k] = sg[mi];
        }
        float inv = 1.f / (bw[0] + bw[1] + bw[2]);
        int tt = t0 + t;
        #pragma unroll
        for (int k = 0; k < 3; k++) {
            tokE[tt * 3 + k] = be[k];
            tokW[tt * 3 + k] = bw[k] * inv;
            sel[t][k] = be[k];
        }
        ginv[t] = 1.f / gsum;
    }
    __syncthreads();
    if (tid < NE) {   // per-block partials: NO global atomics
        float p = 0.f; int c = 0;
        #pragma unroll
        for (int q = 0; q < 8; q++) {
            p += gvv[q][tid] * ginv[q];
            #pragma unroll
            for (int k = 0; k < 3; k++) c += (sel[q][k] == tid);
        }
        Ppart[tid * 1024 + blockIdx.x] = p;
        Cpart[tid * 1024 + blockIdx.x] = c;
    }
}

// cvt tile routine: TWO 64-k tiles of f32 [K][N] -> blocked-transposed bf16
// dst[((e*KBt+kb)*N + n)*64 + p*8 + i] = bf16(W[kb*64 + j*8 + i][n]), p = j ^ (n&7)
__device__ __forceinline__ void cvt_tile(
    const float* __restrict__ src, unsigned short* __restrict__ dst,
    int N, int KBt, int e, int kb0, int n0, void* smem, int tid)
{
    unsigned (*Ls)[32][65] = (unsigned (*)[32][65])smem;  // packed bf16 row-pairs
    const int c = (tid & 15) * 4, r2l = tid >> 4;
    #pragma unroll
    for (int t = 0; t < 2; t++) {
        const float* tsrc = src + (size_t)(kb0 + t) * 64 * N + n0;
        #pragma unroll
        for (int pass = 0; pass < 2; pass++) {
            int row2 = pass * 16 + r2l;
            float4 v0 = *(const float4*)(tsrc + (size_t)(2 * row2) * N + c);
            float4 v1 = *(const float4*)(tsrc + (size_t)(2 * row2 + 1) * N + c);
            uint4 o;
            o.x = bfr2(v0.x, v1.x); o.y = bfr2(v0.y, v1.y);
            o.z = bfr2(v0.z, v1.z); o.w = bfr2(v0.w, v1.w);
            *(uint4*)&Ls[t][row2][c] = o;
        }
    }
    __syncthreads();
    #pragma unroll
    for (int t = 0; t < 2; t++) {
        unsigned short* dbase = dst + ((size_t)(e * KBt + kb0 + t) * N + n0) * 64;
        #pragma unroll
        for (int half = 0; half < 2; half++) {
            int g = half * 256 + tid;
            int n = g >> 3, p = g & 7;
            int j4 = (p ^ (n & 7)) * 4;
            uint4 o;
            o.x = Ls[t][j4 + 0][n]; o.y = Ls[t][j4 + 1][n];
            o.z = Ls[t][j4 + 2][n]; o.w = Ls[t][j4 + 3][n];
            *(uint4*)(dbase + n * 64 + p * 8) = o;
        }
    }
}

// W1/W2 conversion, 4 k-tiles per block
__global__ __launch_bounds__(256) void k_cvt(
    const float* __restrict__ W1, const float* __restrict__ sW1,
    const float* __restrict__ W2, const float* __restrict__ sW2,
    unsigned short* __restrict__ W1b, unsigned short* __restrict__ W2b)
{
    __shared__ __align__(16) char smem[16896];
    const int tid = threadIdx.x;
    int id = blockIdx.x;
    if (id < CVT1_BLKS) {              // W1: K=DD, N=HH
        int n0 = (id % 12) * 64, kb0 = ((id / 12) % 4) * 4, e = id / 48;
        const float* src = (e < NE) ? (W1 + (size_t)e * DD * HH) : sW1;
        cvt_tile(src, W1b, HH, KB1, e, kb0, n0, smem, tid);
        __syncthreads();
        cvt_tile(src, W1b, HH, KB1, e, kb0 + 2, n0, smem, tid);
    } else {                           // W2: K=HH, N=DD
        id -= CVT1_BLKS;
        int n0 = (id % 16) * 64, kb0 = ((id / 16) % 3) * 4, e = id / 48;
        const float* src = (e < NE) ? (W2 + (size_t)e * HH * DD) : sW2;
        cvt_tile(src, W2b, DD, KB2, e, kb0, n0, smem, tid);
        __syncthreads();
        cvt_tile(src, W2b, DD, KB2, e, kb0 + 2, n0, smem, tid);
    }
}

__global__ __launch_bounds__(256) void k_reduce(
    const float* __restrict__ Ppart, const int* __restrict__ Cpart,
    int* __restrict__ counts, float* __restrict__ Psum)
{
    const int e = blockIdx.x;
    const int tid = threadIdx.x;
    float s = 0.f; int c = 0;
    for (int i = tid; i < GATE_BLKS; i += 256) {
        s += Ppart[e * 1024 + i];
        c += Cpart[e * 1024 + i];
    }
    #pragma unroll
    for (int off = 32; off >= 1; off >>= 1) {
        s += __shfl_down(s, off, 64);
        c += __shfl_down(c, off, 64);
    }
    __shared__ float ss[4]; __shared__ int sc[4];
    if ((tid & 63) == 0) { ss[tid >> 6] = s; sc[tid >> 6] = c; }
    __syncthreads();
    if (tid == 0) {
        Psum[e] = ss[0] + ss[1] + ss[2] + ss[3];
        counts[e] = sc[0] + sc[1] + sc[2] + sc[3];
    }
}

__global__ void k_scan(const int* __restrict__ counts, const float* __restrict__ Psum,
                       int* __restrict__ offs, int* __restrict__ total,
                       int* __restrict__ t2e, int* __restrict__ t2a,
                       int* __restrict__ curs, float* __restrict__ outAux)
{
    const int tid = threadIdx.x;
    for (int i = tid; i < NE * 16; i += 256) curs[i] = 0;   // replaces memset
    if (tid != 0) return;
    int off = 0, toff = 0;
    for (int e = 0; e < NG; e++) {
        int c = (e < NE) ? counts[e] : TT;
        offs[e] = off;
        int nt = (c + BM - 1) / BM;
        for (int t = 0; t < nt; t++) {
            t2e[toff + t] = e;
            t2a[toff + t] = off + t * BM;
        }
        off += c; toff += nt;
    }
    offs[NG] = off;
    *total = toff;
    float aux = 0.f;
    for (int e = 0; e < NE; e++) {
        float P = Psum[e] / (float)TT;
        float F = (float)NE * (float)counts[e] / (float)(3 * TT);
        aux += P * F;
    }
    outAux[0] = aux;
    for (int e = 0; e < NE; e++) outAux[1 + e] = (float)counts[e];
}

__global__ void k_scatter(const int* __restrict__ tokE, const float* __restrict__ tokW,
                          const int* __restrict__ offs, int* __restrict__ curs,
                          int* __restrict__ ltok, float* __restrict__ lw,
                          int* __restrict__ sidx)
{
    int t = blockIdx.x * 256 + threadIdx.x;
    if (t >= TT) return;
    #pragma unroll
    for (int k = 0; k < 3; k++) {
        int e = tokE[t * 3 + k];
        int pos = atomicAdd(&curs[e * 16], 1);   // 1 cache line per expert counter
        int idx = offs[e] + pos;
        ltok[idx] = t; lw[idx] = tokW[t * 3 + k];
        sidx[t * 3 + k] = idx;
    }
    ltok[3 * TT + t] = t;
    lw[3 * TT + t] = 1.f;
}

// grouped bf16-MFMA GEMM1 + fast GeLU; T3-minimum 2-phase (r8/r13 structure, best)
__global__ __launch_bounds__(256) void k_mm1(
    const unsigned short* __restrict__ xb, const unsigned short* __restrict__ W1b,
    const float* __restrict__ b1, const float* __restrict__ sb1,
    const int* __restrict__ t2e, const int* __restrict__ t2a,
    const int* __restrict__ offs, const int* __restrict__ total,
    const int* __restrict__ ltok, unsigned short* __restrict__ H)
{
    const int id = blockIdx.x;
    const int wg = (id & 7) * (NWG1 / 8) + (id >> 3);   // XCD-aware bijective swizzle
    const int ns = wg / MAXT;
    const int tb = wg % MAXT;
    if (tb >= *total) return;
    const int e = t2e[tb];
    const int a0 = t2a[tb];
    const int acount = min(offs[e + 1] - a0, BM);
    const float* bb = (e < NE) ? (b1 + e * HH) : sb1;
    const int nb = ns * BN;

    __shared__ unsigned short As[2][BM * BK];
    __shared__ unsigned short Bs[2][BN * BK];
    __shared__ int rows[BM];
    const int tid = threadIdx.x;
    if (tid < BM) rows[tid] = ltok[a0 + min(tid, acount - 1)];  // clamped gather
    __syncthreads();

    const int wid = tid >> 6, lane = tid & 63;
    const int wr = wid >> 1, wc = wid & 1;
    const int l15 = lane & 15, l4 = lane >> 4;

    float bv[4];
    #pragma unroll
    for (int n = 0; n < 4; n++) bv[n] = bb[nb + wc * 64 + n * 16 + l15];

    f32x4 acc[4][4];
    #pragma unroll
    for (int m = 0; m < 4; m++)
        #pragma unroll
        for (int n = 0; n < 4; n++) acc[m][n] = (f32x4){0.f, 0.f, 0.f, 0.f};

    const unsigned short* aSrc[4];
    int Goff[4];
    #pragma unroll
    for (int c = 0; c < 4; c++) {
        int G = (wid * 4 + c) * 64 + lane;
        int row = G >> 3, j = G & 7;
        aSrc[c] = xb + (size_t)rows[row] * DD + ((j ^ (row & 7)) << 3);
        Goff[c] = G * 8;
    }
    const unsigned short* wbase = W1b + ((size_t)e * KB1 * HH + nb) * 64;

    auto stage = [&](int buf, int kb) {   // 8 VMEM ops per thread
        #pragma unroll
        for (int c = 0; c < 4; c++)
            gl_lds16(aSrc[c] + kb * 64, &As[buf][Goff[c]]);
        const unsigned short* wb = wbase + (size_t)kb * (HH * 64);
        #pragma unroll
        for (int c = 0; c < 4; c++)
            gl_lds16(wb + Goff[c], &Bs[buf][Goff[c]]);
    };
    auto compute = [&](int buf) {
        #pragma unroll
        for (int kh = 0; kh < 2; kh++) {
            bf16x8 af[4], bf[4];
            #pragma unroll
            for (int f = 0; f < 4; f++) {
                int ar = wr * 64 + f * 16 + l15;
                int br = wc * 64 + f * 16 + l15;
                int pg = (kh << 2) + l4;
                af[f] = *(const bf16x8*)&As[buf][ar * 64 + ((pg ^ (ar & 7)) << 3)];
                bf[f] = *(const bf16x8*)&Bs[buf][br * 64 + ((pg ^ (br & 7)) << 3)];
            }
            #pragma unroll
            for (int m = 0; m < 4; m++)
                #pragma unroll
                for (int n = 0; n < 4; n++)
                    acc[m][n] = __builtin_amdgcn_mfma_f32_16x16x32_bf16(af[m], bf[n], acc[m][n], 0, 0, 0);
        }
    };

    stage(0, 0);
    WAIT_VM0();
    S_BARRIER();
    int cur = 0;
    #pragma unroll 1
    for (int kb = 0; kb < KB1; kb++) {
        if (kb + 1 < KB1) stage(cur ^ 1, kb + 1);   // issue next-tile loads FIRST
        __builtin_amdgcn_sched_barrier(0);          // pin issue order
        compute(cur);                               // MFMA hides the load latency
        if (kb + 1 < KB1) {
            WAIT_VM0();
            S_BARRIER();
            cur ^= 1;
        }
    }

    #pragma unroll
    for (int m = 0; m < 4; m++) {
        int rbase = wr * 64 + m * 16 + l4 * 4;
        #pragma unroll
        for (int n = 0; n < 4; n++) {
            int col = nb + wc * 64 + n * 16 + l15;
            #pragma unroll
            for (int i = 0; i < 4; i++) {
                int r = rbase + i;
                if (r < acount) {
                    float v = acc[m][n][i] + bv[n];
                    float u = v + 0.044715f * v * v * v;
                    float g = v / (1.f + __expf(-1.5957691216f * u));  // tanh-gelu
                    H[(size_t)(a0 + r) * HH + col] = bfr(g);
                }
            }
        }
    }
}

// grouped bf16-MFMA GEMM2; T3-minimum 2-phase (r8/r13 structure).
__global__ __launch_bounds__(256) void k_mm2(
    const unsigned short* __restrict__ H, const unsigned short* __restrict__ W2b,
    const float* __restrict__ b2, const float* __restrict__ sb2,
    const int* __restrict__ t2e, const int* __restrict__ t2a,
    const int* __restrict__ offs, const int* __restrict__ total,
    const int* __restrict__ ltok, const float* __restrict__ lw,
    unsigned short* __restrict__ yslot, float* __restrict__ out)
{
    const int id = blockIdx.x;
    const int wg = (id & 7) * (NWG2 / 8) + (id >> 3);
    const int ns = wg / MAXT;
    const int tb = wg % MAXT;
    if (tb >= *total) return;
    const int e = t2e[tb];
    const int a0 = t2a[tb];
    const int acount = min(offs[e + 1] - a0, BM);
    const float* bb = (e < NE) ? (b2 + e * DD) : sb2;
    const int nb = ns * BN;

    __shared__ unsigned short As[2][BM * BK];
    __shared__ unsigned short Bs[2][BN * BK];
    __shared__ int rows[BM];
    __shared__ float wts[BM];
    const int tid = threadIdx.x;
    if (tid < BM) {
        rows[tid] = (tid < acount) ? ltok[a0 + tid] : -1;
        wts[tid]  = (tid < acount) ? lw[a0 + tid] : 0.f;
    }
    __syncthreads();

    const int wid = tid >> 6, lane = tid & 63;
    const int wr = wid >> 1, wc = wid & 1;
    const int l15 = lane & 15, l4 = lane >> 4;

    float bv[4];
    #pragma unroll
    for (int n = 0; n < 4; n++) bv[n] = bb[nb + wc * 64 + n * 16 + l15];

    f32x4 acc[4][4];
    #pragma unroll
    for (int m = 0; m < 4; m++)
        #pragma unroll
        for (int n = 0; n < 4; n++) acc[m][n] = (f32x4){0.f, 0.f, 0.f, 0.f};

    const unsigned short* aSrc[4];
    int Goff[4];
    #pragma unroll
    for (int c = 0; c < 4; c++) {
        int G = (wid * 4 + c) * 64 + lane;
        int row = G >> 3, j = G & 7;
        aSrc[c] = H + (size_t)(a0 + row) * HH + ((j ^ (row & 7)) << 3);  // contiguous rows
        Goff[c] = G * 8;
    }
    const unsigned short* wbase = W2b + ((size_t)e * KB2 * DD + nb) * 64;

    auto stage = [&](int buf, int kb) {
        #pragma unroll
        for (int c = 0; c < 4; c++)
            gl_lds16(aSrc[c] + kb * 64, &As[buf][Goff[c]]);
        const unsigned short* wb = wbase + (size_t)kb * (DD * 64);
        #pragma unroll
        for (int c = 0; c < 4; c++)
            gl_lds16(wb + Goff[c], &Bs[buf][Goff[c]]);
    };
    auto compute = [&](int buf) {
        #pragma unroll
        for (int kh = 0; kh < 2; kh++) {
            bf16x8 af[4], bf[4];
            #pragma unroll
            for (int f = 0; f < 4; f++) {
                int ar = wr * 64 + f * 16 + l15;
                int br = wc * 64 + f * 16 + l15;
                int pg = (kh << 2) + l4;
                af[f] = *(const bf16x8*)&As[buf][ar * 64 + ((pg ^ (ar & 7)) << 3)];
                bf[f] = *(const bf16x8*)&Bs[buf][br * 64 + ((pg ^ (br & 7)) << 3)];
            }
            #pragma unroll
            for (int m = 0; m < 4; m++)
                #pragma unroll
                for (int n = 0; n < 4; n++)
                    acc[m][n] = __builtin_amdgcn_mfma_f32_16x16x32_bf16(af[m], bf[n], acc[m][n], 0, 0, 0);
        }
    };

    stage(0, 0);
    WAIT_VM0();
    S_BARRIER();
    int cur = 0;
    #pragma unroll 1
    for (int kb = 0; kb < KB2; kb++) {
        if (kb + 1 < KB2) stage(cur ^ 1, kb + 1);
        __builtin_amdgcn_sched_barrier(0);
        compute(cur);
        if (kb + 1 < KB2) {
            WAIT_VM0();
            S_BARRIER();
            cur ^= 1;
        }
    }

    if (e == NE) {
        // shared expert: every token, weight 1 -> plain f32 stores (covers whole out body)
        #pragma unroll
        for (int m = 0; m < 4; m++) {
            int rbase = wr * 64 + m * 16 + l4 * 4;
            #pragma unroll
            for (int n = 0; n < 4; n++) {
                int col = nb + wc * 64 + n * 16 + l15;
                #pragma unroll
                for (int i = 0; i < 4; i++) {
                    int r = rbase + i;
                    out[(size_t)rows[r] * DD + col] = acc[m][n][i] + bv[n];
                }
            }
        }
    } else {
        // expert tile: weighted bf16 partial into its slot row (no races, no atomics)
        #pragma unroll
        for (int m = 0; m < 4; m++) {
            int rbase = wr * 64 + m * 16 + l4 * 4;
            #pragma unroll
            for (int n = 0; n < 4; n++) {
                int col = nb + wc * 64 + n * 16 + l15;
                #pragma unroll
                for (int i = 0; i < 4; i++) {
                    int r = rbase + i;
                    if (r < acount)
                        yslot[(size_t)(a0 + r) * DD + col] = bfr(wts[r] * (acc[m][n][i] + bv[n]));
                }
            }
        }
    }
}

// out[t,:] += sum_k yslot[sidx[t,k],:]
__global__ __launch_bounds__(256) void k_combine(
    const unsigned short* __restrict__ yslot, const int* __restrict__ sidx,
    float* __restrict__ out)
{
    const int t = blockIdx.x;
    const int s0 = sidx[t * 3 + 0], s1 = sidx[t * 3 + 1], s2 = sidx[t * 3 + 2];
    const int d = threadIdx.x * 4;
    float* o = out + (size_t)t * DD + d;
    float4 v = *(float4*)o;
    ushort4 a = *(const ushort4*)(yslot + (size_t)s0 * DD + d);
    ushort4 b = *(const ushort4*)(yslot + (size_t)s1 * DD + d);
    ushort4 c = *(const ushort4*)(yslot + (size_t)s2 * DD + d);
    v.x += b2f(a.x) + b2f(b.x) + b2f(c.x);
    v.y += b2f(a.y) + b2f(b.y) + b2f(c.y);
    v.z += b2f(a.z) + b2f(b.z) + b2f(c.z);
    v.w += b2f(a.w) + b2f(b.w) + b2f(c.w);
    *(float4*)o = v;
}

extern "C" void kernel_launch(void* const* d_in, const int* in_sizes, int n_in,
                              void* d_out, int out_size, void* d_ws, size_t ws_size,
                              hipStream_t stream)
{
    const float* x    = (const float*)d_in[0];
    const float* gW   = (const float*)d_in[1];
    const float* gb   = (const float*)d_in[2];
    const float* bias = (const float*)d_in[3];
    const float* W1   = (const float*)d_in[4];
    const float* b1   = (const float*)d_in[5];
    const float* W2   = (const float*)d_in[6];
    const float* b2   = (const float*)d_in[7];
    const float* sW1  = (const float*)d_in[8];
    const float* sb1  = (const float*)d_in[9];
    const float* sW2  = (const float*)d_in[10];
    const float* sb2  = (const float*)d_in[11];
    float* out = (float*)d_out;
    float* wsf = (float*)d_ws;
    int*   wsi = (int*)d_ws;

    int*   curs   = wsi + WS_CURS;
    int*   offs   = wsi + WS_OFFS;
    int*   total  = wsi + WS_TOTAL;
    int*   t2e    = wsi + WS_T2E;
    int*   t2a    = wsi + WS_T2A;
    int*   tokE   = wsi + WS_TOKE;
    float* tokW   = wsf + WS_TOKW;
    int*   ltok   = wsi + WS_LTOK;
    float* lwt    = wsf + WS_LW;
    float* Ppart  = wsf + WS_PPART;
    int*   Cpart  = wsi + WS_CPART;
    int*   sidx   = wsi + WS_SIDX;
    int*   counts = wsi + 432;
    float* Psum   = wsf + 464;
    unsigned short* xb  = (unsigned short*)((char*)d_ws + XB_OFF);
    unsigned short* Hb  = (unsigned short*)((char*)d_ws + H_OFF);
    unsigned short* W1b = (unsigned short*)((char*)d_ws + W1B_OFF);
    unsigned short* W2b = (unsigned short*)((char*)d_ws + W2B_OFF);
    unsigned short* yslot = W1b;   // reuse W1b region after k_mm1 is done

    k_gate<<<GATE_BLKS, 256, 0, stream>>>(x, gW, gb, bias, tokE, tokW,
                                          Ppart, Cpart, xb);
    k_cvt<<<CVT_TOT, 256, 0, stream>>>(W1, sW1, W2, sW2, W1b, W2b);
    k_reduce<<<NE, 256, 0, stream>>>(Ppart, Cpart, counts, Psum);
    k_scan<<<1, 256, 0, stream>>>(counts, Psum, offs, total, t2e, t2a, curs,
                                  out + (size_t)TT * DD);
    k_scatter<<<TT / 256, 256, 0, stream>>>(tokE, tokW, offs, curs, ltok, lwt, sidx);
    k_mm1<<<NWG1, 256, 0, stream>>>(xb, W1b, b1, sb1, t2e, t2a, offs, total, ltok, Hb);
    k_mm2<<<NWG2, 256, 0, stream>>>(Hb, W2b, b2, sb2, t2e, t2a, offs, total, ltok, lwt,
                                    yslot, out);
    k_combine<<<TT, 256, 0, stream>>>(yslot, sidx, out);
}

// Round 18
// 217.328 us; speedup vs baseline: 1.0074x; 1.0074x over previous
//
#include <hip/hip_runtime.h>
#include <math.h>

#define TT 4096
#define DD 1024
#define HH 768
#define NE 23
#define NG 24          // 23 experts + shared as group 23
#define BM 128
#define BN 128
#define BK 64
#define MAXT 160       // sum ceil(n_e/128) <= 119, + 32 shared tiles = 151
#define KB1 16         // DD/64
#define KB2 12         // HH/64
#define NY1 6          // HH/BN
#define NY2 8          // DD/BN
#define NWG1 (MAXT*NY1)   // 960  (div by 8)
#define NWG2 (MAXT*NY2)   // 1280 (div by 8)
#define GATE_BLKS 512     // 8 tokens per block
#define CVT1_BLKS 1152    // W1: 12 nblk * 4 kquad * 24 e
#define CVT_TOT   2304    // + W2: 16 nblk * 3 kquad * 24 e

// ws word offsets (misc, < 512KB)
#define WS_CURS   0        // 23*16 ints (1 cache line per expert)
#define WS_OFFS   576
#define WS_TOTAL  640
#define WS_T2E    672      // tile -> expert/group
#define WS_T2A    832      // tile -> a0
#define WS_TOKE   1024
#define WS_TOKW   13312
#define WS_LTOK   25600
#define WS_LW     41984
#define WS_PPART  58368    // 23*1024 floats (only [0,512) used per expert)
#define WS_CPART  81920    // 23*1024 ints
#define WS_SIDX   106496   // 12288 ints (ends 118784 < 131072)
// ws byte offsets (big buffers)
#define XB_OFF  ((size_t)524288)      // xb bf16: 4096*1024*2  = 8388608
#define H_OFF   ((size_t)8912896)     // H bf16
#define W1B_OFF ((size_t)34078720)    // W1 blocked bf16 (reused after mm1 as yslot)
#define W2B_OFF ((size_t)71827456)    // W2 blocked bf16

typedef short bf16x8 __attribute__((ext_vector_type(8)));
typedef float f32x4 __attribute__((ext_vector_type(4)));

#define S_BARRIER() asm volatile("s_barrier" ::: "memory")
#define WAIT_VM0()  asm volatile("s_waitcnt vmcnt(0)" ::: "memory")

__device__ inline unsigned short bfr(float f) {   // f32 -> bf16 RNE
    unsigned u = __float_as_uint(f);
    u += 0x7fffu + ((u >> 16) & 1u);
    return (unsigned short)(u >> 16);
}
__device__ inline unsigned bfr2(float lo, float hi) {  // pack 2 bf16 into dword
    return (unsigned)bfr(lo) | ((unsigned)bfr(hi) << 16);
}
__device__ inline float b2f(unsigned short u) {
    return __uint_as_float((unsigned)u << 16);
}

__device__ __forceinline__ void gl_lds16(const void* g, void* l) {
    __builtin_amdgcn_global_load_lds(
        (const __attribute__((address_space(1))) unsigned int*)g,
        (__attribute__((address_space(3))) unsigned int*)l, 16, 0, 0);
}

// Exact-f32 gate, LDS-resident gW. 8 tokens/block, all 64 lanes active.
// gW staged via 23 UNROLLED coalesced float4 loads/thread (fix for r17's
// 92-sequential-scalar-load staging at 1 wave/SIMD).
__global__ __launch_bounds__(256) void k_gate(
    const float* __restrict__ x, const float* __restrict__ gW,
    const float* __restrict__ gb, const float* __restrict__ bias,
    int* __restrict__ tokE, float* __restrict__ tokW,
    float* __restrict__ Ppart, int* __restrict__ Cpart,
    unsigned short* __restrict__ xb)
{
    __shared__ float gwp[DD * 28];    // 112 KB: [d][28], e in [0,23)
    __shared__ float xs[8 * DD];      // 32 KB
    __shared__ float gvv[8][24];
    __shared__ float ginv[8];
    __shared__ int   sel[8][3];
    const int tid = threadIdx.x;
    const int t0 = blockIdx.x * 8;

    {   // stage 8 token rows of x (coalesced) + write bf16 copy
        const float4* sx = (const float4*)(x + (size_t)t0 * DD);
        float4* dx = (float4*)xs;
        unsigned short* xd = xb + (size_t)t0 * DD;
        #pragma unroll
        for (int c = 0; c < 8; c++) {
            int idx = c * 256 + tid;
            float4 v = sx[idx];
            dx[idx] = v;
            ushort4 u = make_ushort4(bfr(v.x), bfr(v.y), bfr(v.z), bfr(v.w));
            *(ushort4*)(xd + idx * 4) = u;
        }
    }
    {   // stage gW -> [d][28] via float4 (23*256*4 == DD*NE exactly)
        const float4* g4 = (const float4*)gW;
        #pragma unroll
        for (int k = 0; k < 23; k++) {
            int i4 = k * 256 + tid;
            float4 v = g4[i4];
            int base = i4 * 4;
            #pragma unroll
            for (int j = 0; j < 4; j++) {
                int idx = base + j;
                int d = idx / NE;           // magic-mul (constant divisor)
                int e = idx - d * NE;
                gwp[d * 28 + e] = (&v.x)[j];
            }
        }
    }
    __syncthreads();

    const int t = tid >> 5, s = tid & 31;
    float acc[24];
    #pragma unroll
    for (int e = 0; e < 24; e++) acc[e] = 0.f;
    const float* xrow = xs + t * DD;
    #pragma unroll 2
    for (int j = 0; j < 32; j++) {
        int d = j * 32 + s;
        float xv = xrow[d];                    // bank = s: conflict-free
        const float* gr = gwp + d * 28;
        float g[24];
        #pragma unroll
        for (int q = 0; q < 6; q++) {          // 4-way bank conflict (1.58x) - ok
            float4 v = *(const float4*)(gr + q * 4);
            g[4*q] = v.x; g[4*q+1] = v.y; g[4*q+2] = v.z; g[4*q+3] = v.w;
        }
        #pragma unroll
        for (int e = 0; e < 24; e++) acc[e] = fmaf(xv, g[e], acc[e]);
    }
    #pragma unroll
    for (int e = 0; e < 23; e++) {             // reduce over the 32 s-lanes
        #pragma unroll
        for (int off = 16; off >= 1; off >>= 1)
            acc[e] += __shfl_xor(acc[e], off, 32);
    }
    __syncthreads();
    if (s == 0) {
        float sg[23]; float gsum = 0.f;
        #pragma unroll
        for (int e = 0; e < 23; e++) {
            float sv = 1.f / (1.f + expf(-(acc[e] + gb[e])));
            sg[e] = sv; gvv[t][e] = sv; gsum += sv;
        }
        unsigned chosen = 0; int be[3]; float bw[3];
        #pragma unroll
        for (int k = 0; k < 3; k++) {
            float m = -1e30f; int mi = 0;
            for (int e = 0; e < 23; e++) {
                float kv = sg[e] + bias[e];
                if (!((chosen >> e) & 1u) && kv > m) { m = kv; mi = e; }
            }
            chosen |= 1u << mi; be[k] = mi; bw[k] = sg[mi];
        }
        float inv = 1.f / (bw[0] + bw[1] + bw[2]);
        int tt = t0 + t;
        #pragma unroll
        for (int k = 0; k < 3; k++) {
            tokE[tt * 3 + k] = be[k];
            tokW[tt * 3 + k] = bw[k] * inv;
            sel[t][k] = be[k];
        }
        ginv[t] = 1.f / gsum;
    }
    __syncthreads();
    if (tid < NE) {   // per-block partials: NO global atomics
        float p = 0.f; int c = 0;
        #pragma unroll
        for (int q = 0; q < 8; q++) {
            p += gvv[q][tid] * ginv[q];
            #pragma unroll
            for (int k = 0; k < 3; k++) c += (sel[q][k] == tid);
        }
        Ppart[tid * 1024 + blockIdx.x] = p;
        Cpart[tid * 1024 + blockIdx.x] = c;
    }
}

// cvt tile routine: TWO 64-k tiles of f32 [K][N] -> blocked-transposed bf16
// dst[((e*KBt+kb)*N + n)*64 + p*8 + i] = bf16(W[kb*64 + j*8 + i][n]), p = j ^ (n&7)
__device__ __forceinline__ void cvt_tile(
    const float* __restrict__ src, unsigned short* __restrict__ dst,
    int N, int KBt, int e, int kb0, int n0, void* smem, int tid)
{
    unsigned (*Ls)[32][65] = (unsigned (*)[32][65])smem;  // packed bf16 row-pairs
    const int c = (tid & 15) * 4, r2l = tid >> 4;
    #pragma unroll
    for (int t = 0; t < 2; t++) {
        const float* tsrc = src + (size_t)(kb0 + t) * 64 * N + n0;
        #pragma unroll
        for (int pass = 0; pass < 2; pass++) {
            int row2 = pass * 16 + r2l;
            float4 v0 = *(const float4*)(tsrc + (size_t)(2 * row2) * N + c);
            float4 v1 = *(const float4*)(tsrc + (size_t)(2 * row2 + 1) * N + c);
            uint4 o;
            o.x = bfr2(v0.x, v1.x); o.y = bfr2(v0.y, v1.y);
            o.z = bfr2(v0.z, v1.z); o.w = bfr2(v0.w, v1.w);
            *(uint4*)&Ls[t][row2][c] = o;
        }
    }
    __syncthreads();
    #pragma unroll
    for (int t = 0; t < 2; t++) {
        unsigned short* dbase = dst + ((size_t)(e * KBt + kb0 + t) * N + n0) * 64;
        #pragma unroll
        for (int half = 0; half < 2; half++) {
            int g = half * 256 + tid;
            int n = g >> 3, p = g & 7;
            int j4 = (p ^ (n & 7)) * 4;
            uint4 o;
            o.x = Ls[t][j4 + 0][n]; o.y = Ls[t][j4 + 1][n];
            o.z = Ls[t][j4 + 2][n]; o.w = Ls[t][j4 + 3][n];
            *(uint4*)(dbase + n * 64 + p * 8) = o;
        }
    }
}

// W1/W2 conversion, 4 k-tiles per block
__global__ __launch_bounds__(256) void k_cvt(
    const float* __restrict__ W1, const float* __restrict__ sW1,
    const float* __restrict__ W2, const float* __restrict__ sW2,
    unsigned short* __restrict__ W1b, unsigned short* __restrict__ W2b)
{
    __shared__ __align__(16) char smem[16896];
    const int tid = threadIdx.x;
    int id = blockIdx.x;
    if (id < CVT1_BLKS) {              // W1: K=DD, N=HH
        int n0 = (id % 12) * 64, kb0 = ((id / 12) % 4) * 4, e = id / 48;
        const float* src = (e < NE) ? (W1 + (size_t)e * DD * HH) : sW1;
        cvt_tile(src, W1b, HH, KB1, e, kb0, n0, smem, tid);
        __syncthreads();
        cvt_tile(src, W1b, HH, KB1, e, kb0 + 2, n0, smem, tid);
    } else {                           // W2: K=HH, N=DD
        id -= CVT1_BLKS;
        int n0 = (id % 16) * 64, kb0 = ((id / 16) % 3) * 4, e = id / 48;
        const float* src = (e < NE) ? (W2 + (size_t)e * HH * DD) : sW2;
        cvt_tile(src, W2b, DD, KB2, e, kb0, n0, smem, tid);
        __syncthreads();
        cvt_tile(src, W2b, DD, KB2, e, kb0 + 2, n0, smem, tid);
    }
}

__global__ __launch_bounds__(256) void k_reduce(
    const float* __restrict__ Ppart, const int* __restrict__ Cpart,
    int* __restrict__ counts, float* __restrict__ Psum)
{
    const int e = blockIdx.x;
    const int tid = threadIdx.x;
    float s = 0.f; int c = 0;
    for (int i = tid; i < GATE_BLKS; i += 256) {
        s += Ppart[e * 1024 + i];
        c += Cpart[e * 1024 + i];
    }
    #pragma unroll
    for (int off = 32; off >= 1; off >>= 1) {
        s += __shfl_down(s, off, 64);
        c += __shfl_down(c, off, 64);
    }
    __shared__ float ss[4]; __shared__ int sc[4];
    if ((tid & 63) == 0) { ss[tid >> 6] = s; sc[tid >> 6] = c; }
    __syncthreads();
    if (tid == 0) {
        Psum[e] = ss[0] + ss[1] + ss[2] + ss[3];
        counts[e] = sc[0] + sc[1] + sc[2] + sc[3];
    }
}

__global__ void k_scan(const int* __restrict__ counts, const float* __restrict__ Psum,
                       int* __restrict__ offs, int* __restrict__ total,
                       int* __restrict__ t2e, int* __restrict__ t2a,
                       int* __restrict__ curs, float* __restrict__ outAux)
{
    const int tid = threadIdx.x;
    for (int i = tid; i < NE * 16; i += 256) curs[i] = 0;   // replaces memset
    if (tid != 0) return;
    int off = 0, toff = 0;
    for (int e = 0; e < NG; e++) {
        int c = (e < NE) ? counts[e] : TT;
        offs[e] = off;
        int nt = (c + BM - 1) / BM;
        for (int t = 0; t < nt; t++) {
            t2e[toff + t] = e;
            t2a[toff + t] = off + t * BM;
        }
        off += c; toff += nt;
    }
    offs[NG] = off;
    *total = toff;
    float aux = 0.f;
    for (int e = 0; e < NE; e++) {
        float P = Psum[e] / (float)TT;
        float F = (float)NE * (float)counts[e] / (float)(3 * TT);
        aux += P * F;
    }
    outAux[0] = aux;
    for (int e = 0; e < NE; e++) outAux[1 + e] = (float)counts[e];
}

__global__ void k_scatter(const int* __restrict__ tokE, const float* __restrict__ tokW,
                          const int* __restrict__ offs, int* __restrict__ curs,
                          int* __restrict__ ltok, float* __restrict__ lw,
                          int* __restrict__ sidx)
{
    int t = blockIdx.x * 256 + threadIdx.x;
    if (t >= TT) return;
    #pragma unroll
    for (int k = 0; k < 3; k++) {
        int e = tokE[t * 3 + k];
        int pos = atomicAdd(&curs[e * 16], 1);   // 1 cache line per expert counter
        int idx = offs[e] + pos;
        ltok[idx] = t; lw[idx] = tokW[t * 3 + k];
        sidx[t * 3 + k] = idx;
    }
    ltok[3 * TT + t] = t;
    lw[3 * TT + t] = 1.f;
}

// grouped bf16-MFMA GEMM1 + fast GeLU; T3-minimum 2-phase (r8/r13 structure, best)
__global__ __launch_bounds__(256) void k_mm1(
    const unsigned short* __restrict__ xb, const unsigned short* __restrict__ W1b,
    const float* __restrict__ b1, const float* __restrict__ sb1,
    const int* __restrict__ t2e, const int* __restrict__ t2a,
    const int* __restrict__ offs, const int* __restrict__ total,
    const int* __restrict__ ltok, unsigned short* __restrict__ H)
{
    const int id = blockIdx.x;
    const int wg = (id & 7) * (NWG1 / 8) + (id >> 3);   // XCD-aware bijective swizzle
    const int ns = wg / MAXT;
    const int tb = wg % MAXT;
    if (tb >= *total) return;
    const int e = t2e[tb];
    const int a0 = t2a[tb];
    const int acount = min(offs[e + 1] - a0, BM);
    const float* bb = (e < NE) ? (b1 + e * HH) : sb1;
    const int nb = ns * BN;

    __shared__ unsigned short As[2][BM * BK];
    __shared__ unsigned short Bs[2][BN * BK];
    __shared__ int rows[BM];
    const int tid = threadIdx.x;
    if (tid < BM) rows[tid] = ltok[a0 + min(tid, acount - 1)];  // clamped gather
    __syncthreads();

    const int wid = tid >> 6, lane = tid & 63;
    const int wr = wid >> 1, wc = wid & 1;
    const int l15 = lane & 15, l4 = lane >> 4;

    float bv[4];
    #pragma unroll
    for (int n = 0; n < 4; n++) bv[n] = bb[nb + wc * 64 + n * 16 + l15];

    f32x4 acc[4][4];
    #pragma unroll
    for (int m = 0; m < 4; m++)
        #pragma unroll
        for (int n = 0; n < 4; n++) acc[m][n] = (f32x4){0.f, 0.f, 0.f, 0.f};

    const unsigned short* aSrc[4];
    int Goff[4];
    #pragma unroll
    for (int c = 0; c < 4; c++) {
        int G = (wid * 4 + c) * 64 + lane;
        int row = G >> 3, j = G & 7;
        aSrc[c] = xb + (size_t)rows[row] * DD + ((j ^ (row & 7)) << 3);
        Goff[c] = G * 8;
    }
    const unsigned short* wbase = W1b + ((size_t)e * KB1 * HH + nb) * 64;

    auto stage = [&](int buf, int kb) {   // 8 VMEM ops per thread
        #pragma unroll
        for (int c = 0; c < 4; c++)
            gl_lds16(aSrc[c] + kb * 64, &As[buf][Goff[c]]);
        const unsigned short* wb = wbase + (size_t)kb * (HH * 64);
        #pragma unroll
        for (int c = 0; c < 4; c++)
            gl_lds16(wb + Goff[c], &Bs[buf][Goff[c]]);
    };
    auto compute = [&](int buf) {
        #pragma unroll
        for (int kh = 0; kh < 2; kh++) {
            bf16x8 af[4], bf[4];
            #pragma unroll
            for (int f = 0; f < 4; f++) {
                int ar = wr * 64 + f * 16 + l15;
                int br = wc * 64 + f * 16 + l15;
                int pg = (kh << 2) + l4;
                af[f] = *(const bf16x8*)&As[buf][ar * 64 + ((pg ^ (ar & 7)) << 3)];
                bf[f] = *(const bf16x8*)&Bs[buf][br * 64 + ((pg ^ (br & 7)) << 3)];
            }
            #pragma unroll
            for (int m = 0; m < 4; m++)
                #pragma unroll
                for (int n = 0; n < 4; n++)
                    acc[m][n] = __builtin_amdgcn_mfma_f32_16x16x32_bf16(af[m], bf[n], acc[m][n], 0, 0, 0);
        }
    };

    stage(0, 0);
    WAIT_VM0();
    S_BARRIER();
    int cur = 0;
    #pragma unroll 1
    for (int kb = 0; kb < KB1; kb++) {
        if (kb + 1 < KB1) stage(cur ^ 1, kb + 1);   // issue next-tile loads FIRST
        __builtin_amdgcn_sched_barrier(0);          // pin issue order
        compute(cur);                               // MFMA hides the load latency
        if (kb + 1 < KB1) {
            WAIT_VM0();
            S_BARRIER();
            cur ^= 1;
        }
    }

    #pragma unroll
    for (int m = 0; m < 4; m++) {
        int rbase = wr * 64 + m * 16 + l4 * 4;
        #pragma unroll
        for (int n = 0; n < 4; n++) {
            int col = nb + wc * 64 + n * 16 + l15;
            #pragma unroll
            for (int i = 0; i < 4; i++) {
                int r = rbase + i;
                if (r < acount) {
                    float v = acc[m][n][i] + bv[n];
                    float u = v + 0.044715f * v * v * v;
                    float g = v / (1.f + __expf(-1.5957691216f * u));  // tanh-gelu
                    H[(size_t)(a0 + r) * HH + col] = bfr(g);
                }
            }
        }
    }
}

// grouped bf16-MFMA GEMM2; T3-minimum 2-phase (r8/r13 structure).
__global__ __launch_bounds__(256) void k_mm2(
    const unsigned short* __restrict__ H, const unsigned short* __restrict__ W2b,
    const float* __restrict__ b2, const float* __restrict__ sb2,
    const int* __restrict__ t2e, const int* __restrict__ t2a,
    const int* __restrict__ offs, const int* __restrict__ total,
    const int* __restrict__ ltok, const float* __restrict__ lw,
    unsigned short* __restrict__ yslot, float* __restrict__ out)
{
    const int id = blockIdx.x;
    const int wg = (id & 7) * (NWG2 / 8) + (id >> 3);
    const int ns = wg / MAXT;
    const int tb = wg % MAXT;
    if (tb >= *total) return;
    const int e = t2e[tb];
    const int a0 = t2a[tb];
    const int acount = min(offs[e + 1] - a0, BM);
    const float* bb = (e < NE) ? (b2 + e * DD) : sb2;
    const int nb = ns * BN;

    __shared__ unsigned short As[2][BM * BK];
    __shared__ unsigned short Bs[2][BN * BK];
    __shared__ int rows[BM];
    __shared__ float wts[BM];
    const int tid = threadIdx.x;
    if (tid < BM) {
        rows[tid] = (tid < acount) ? ltok[a0 + tid] : -1;
        wts[tid]  = (tid < acount) ? lw[a0 + tid] : 0.f;
    }
    __syncthreads();

    const int wid = tid >> 6, lane = tid & 63;
    const int wr = wid >> 1, wc = wid & 1;
    const int l15 = lane & 15, l4 = lane >> 4;

    float bv[4];
    #pragma unroll
    for (int n = 0; n < 4; n++) bv[n] = bb[nb + wc * 64 + n * 16 + l15];

    f32x4 acc[4][4];
    #pragma unroll
    for (int m = 0; m < 4; m++)
        #pragma unroll
        for (int n = 0; n < 4; n++) acc[m][n] = (f32x4){0.f, 0.f, 0.f, 0.f};

    const unsigned short* aSrc[4];
    int Goff[4];
    #pragma unroll
    for (int c = 0; c < 4; c++) {
        int G = (wid * 4 + c) * 64 + lane;
        int row = G >> 3, j = G & 7;
        aSrc[c] = H + (size_t)(a0 + row) * HH + ((j ^ (row & 7)) << 3);  // contiguous rows
        Goff[c] = G * 8;
    }
    const unsigned short* wbase = W2b + ((size_t)e * KB2 * DD + nb) * 64;

    auto stage = [&](int buf, int kb) {
        #pragma unroll
        for (int c = 0; c < 4; c++)
            gl_lds16(aSrc[c] + kb * 64, &As[buf][Goff[c]]);
        const unsigned short* wb = wbase + (size_t)kb * (DD * 64);
        #pragma unroll
        for (int c = 0; c < 4; c++)
            gl_lds16(wb + Goff[c], &Bs[buf][Goff[c]]);
    };
    auto compute = [&](int buf) {
        #pragma unroll
        for (int kh = 0; kh < 2; kh++) {
            bf16x8 af[4], bf[4];
            #pragma unroll
            for (int f = 0; f < 4; f++) {
                int ar = wr * 64 + f * 16 + l15;
                int br = wc * 64 + f * 16 + l15;
                int pg = (kh << 2) + l4;
                af[f] = *(const bf16x8*)&As[buf][ar * 64 + ((pg ^ (ar & 7)) << 3)];
                bf[f] = *(const bf16x8*)&Bs[buf][br * 64 + ((pg ^ (br & 7)) << 3)];
            }
            #pragma unroll
            for (int m = 0; m < 4; m++)
                #pragma unroll
                for (int n = 0; n < 4; n++)
                    acc[m][n] = __builtin_amdgcn_mfma_f32_16x16x32_bf16(af[m], bf[n], acc[m][n], 0, 0, 0);
        }
    };

    stage(0, 0);
    WAIT_VM0();
    S_BARRIER();
    int cur = 0;
    #pragma unroll 1
    for (int kb = 0; kb < KB2; kb++) {
        if (kb + 1 < KB2) stage(cur ^ 1, kb + 1);
        __builtin_amdgcn_sched_barrier(0);
        compute(cur);
        if (kb + 1 < KB2) {
            WAIT_VM0();
            S_BARRIER();
            cur ^= 1;
        }
    }

    if (e == NE) {
        // shared expert: every token, weight 1 -> plain f32 stores (covers whole out body)
        #pragma unroll
        for (int m = 0; m < 4; m++) {
            int rbase = wr * 64 + m * 16 + l4 * 4;
            #pragma unroll
            for (int n = 0; n < 4; n++) {
                int col = nb + wc * 64 + n * 16 + l15;
                #pragma unroll
                for (int i = 0; i < 4; i++) {
                    int r = rbase + i;
                    out[(size_t)rows[r] * DD + col] = acc[m][n][i] + bv[n];
                }
            }
        }
    } else {
        // expert tile: weighted bf16 partial into its slot row (no races, no atomics)
        #pragma unroll
        for (int m = 0; m < 4; m++) {
            int rbase = wr * 64 + m * 16 + l4 * 4;
            #pragma unroll
            for (int n = 0; n < 4; n++) {
                int col = nb + wc * 64 + n * 16 + l15;
                #pragma unroll
                for (int i = 0; i < 4; i++) {
                    int r = rbase + i;
                    if (r < acount)
                        yslot[(size_t)(a0 + r) * DD + col] = bfr(wts[r] * (acc[m][n][i] + bv[n]));
                }
            }
        }
    }
}

// out[t,:] += sum_k yslot[sidx[t,k],:]
__global__ __launch_bounds__(256) void k_combine(
    const unsigned short* __restrict__ yslot, const int* __restrict__ sidx,
    float* __restrict__ out)
{
    const int t = blockIdx.x;
    const int s0 = sidx[t * 3 + 0], s1 = sidx[t * 3 + 1], s2 = sidx[t * 3 + 2];
    const int d = threadIdx.x * 4;
    float* o = out + (size_t)t * DD + d;
    float4 v = *(float4*)o;
    ushort4 a = *(const ushort4*)(yslot + (size_t)s0 * DD + d);
    ushort4 b = *(const ushort4*)(yslot + (size_t)s1 * DD + d);
    ushort4 c = *(const ushort4*)(yslot + (size_t)s2 * DD + d);
    v.x += b2f(a.x) + b2f(b.x) + b2f(c.x);
    v.y += b2f(a.y) + b2f(b.y) + b2f(c.y);
    v.z += b2f(a.z) + b2f(b.z) + b2f(c.z);
    v.w += b2f(a.w) + b2f(b.w) + b2f(c.w);
    *(float4*)o = v;
}

extern "C" void kernel_launch(void* const* d_in, const int* in_sizes, int n_in,
                              void* d_out, int out_size, void* d_ws, size_t ws_size,
                              hipStream_t stream)
{
    const float* x    = (const float*)d_in[0];
    const float* gW   = (const float*)d_in[1];
    const float* gb   = (const float*)d_in[2];
    const float* bias = (const float*)d_in[3];
    const float* W1   = (const float*)d_in[4];
    const float* b1   = (const float*)d_in[5];
    const float* W2   = (const float*)d_in[6];
    const float* b2   = (const float*)d_in[7];
    const float* sW1  = (const float*)d_in[8];
    const float* sb1  = (const float*)d_in[9];
    const float* sW2  = (const float*)d_in[10];
    const float* sb2  = (const float*)d_in[11];
    float* out = (float*)d_out;
    float* wsf = (float*)d_ws;
    int*   wsi = (int*)d_ws;

    int*   curs   = wsi + WS_CURS;
    int*   offs   = wsi + WS_OFFS;
    int*   total  = wsi + WS_TOTAL;
    int*   t2e    = wsi + WS_T2E;
    int*   t2a    = wsi + WS_T2A;
    int*   tokE   = wsi + WS_TOKE;
    float* tokW   = wsf + WS_TOKW;
    int*   ltok   = wsi + WS_LTOK;
    float* lwt    = wsf + WS_LW;
    float* Ppart  = wsf + WS_PPART;
    int*   Cpart  = wsi + WS_CPART;
    int*   sidx   = wsi + WS_SIDX;
    int*   counts = wsi + 432;
    float* Psum   = wsf + 464;
    unsigned short* xb  = (unsigned short*)((char*)d_ws + XB_OFF);
    unsigned short* Hb  = (unsigned short*)((char*)d_ws + H_OFF);
    unsigned short* W1b = (unsigned short*)((char*)d_ws + W1B_OFF);
    unsigned short* W2b = (unsigned short*)((char*)d_ws + W2B_OFF);
    unsigned short* yslot = W1b;   // reuse W1b region after k_mm1 is done

    k_gate<<<GATE_BLKS, 256, 0, stream>>>(x, gW, gb, bias, tokE, tokW,
                                          Ppart, Cpart, xb);
    k_cvt<<<CVT_TOT, 256, 0, stream>>>(W1, sW1, W2, sW2, W1b, W2b);
    k_reduce<<<NE, 256, 0, stream>>>(Ppart, Cpart, counts, Psum);
    k_scan<<<1, 256, 0, stream>>>(counts, Psum, offs, total, t2e, t2a, curs,
                                  out + (size_t)TT * DD);
    k_scatter<<<TT / 256, 256, 0, stream>>>(tokE, tokW, offs, curs, ltok, lwt, sidx);
    k_mm1<<<NWG1, 256, 0, stream>>>(xb, W1b, b1, sb1, t2e, t2a, offs, total, ltok, Hb);
    k_mm2<<<NWG2, 256, 0, stream>>>(Hb, W2b, b2, sb2, t2e, t2a, offs, total, ltok, lwt,
                                    yslot, out);
    k_combine<<<TT, 256, 0, stream>>>(yslot, sidx, out);
}

// Round 19
// 212.662 us; speedup vs baseline: 1.0295x; 1.0219x over previous
//
#include <hip/hip_runtime.h>
#include <math.h>

#define TT 4096
#define DD 1024
#define HH 768
#define NE 23
#define NG 24          // 23 experts + shared as group 23
#define BM 128
#define BN 128
#define BK 64
#define MAXT 160       // sum ceil(n_e/128) <= 119, + 32 shared tiles = 151
#define KB1 16         // DD/64
#define KB2 12         // HH/64
#define NY1 6          // HH/BN
#define NY2 8          // DD/BN
#define NWG1 (MAXT*NY1)   // 960  (div by 8)
#define NWG2 (MAXT*NY2)   // 1280 (div by 8)
#define GATE_BLKS 1024    // TT/4, first in grid (overlaps cvt)
#define CVT1_BLKS 1152    // W1: 12 nblk * 4 kquad * 24 e
#define CVT_TOT   2304    // + W2: 16 nblk * 3 kquad * 24 e

// ws word offsets (misc, < 512KB)
#define WS_CURS   0        // 23*16 ints (1 cache line per expert)
#define WS_OFFS   576
#define WS_TOTAL  640
#define WS_T2E    672      // tile -> expert/group
#define WS_T2A    832      // tile -> a0
#define WS_TOKE   1024
#define WS_TOKW   13312
#define WS_LTOK   25600
#define WS_LW     41984
#define WS_PPART  58368    // 23*1024 floats
#define WS_CPART  81920    // 23*1024 ints
#define WS_SIDX   106496   // 12288 ints (ends 118784 < 131072)
// ws byte offsets (big buffers)
#define XB_OFF  ((size_t)524288)      // xb bf16: 4096*1024*2  = 8388608
#define H_OFF   ((size_t)8912896)     // H bf16
#define W1B_OFF ((size_t)34078720)    // W1 blocked bf16 (reused after mm1 as yslot)
#define W2B_OFF ((size_t)71827456)    // W2 blocked bf16

typedef short bf16x8 __attribute__((ext_vector_type(8)));
typedef float f32x4 __attribute__((ext_vector_type(4)));

#define S_BARRIER() asm volatile("s_barrier" ::: "memory")
#define WAIT_VM0()  asm volatile("s_waitcnt vmcnt(0)" ::: "memory")

__device__ inline unsigned short bfr(float f) {   // f32 -> bf16 RNE
    unsigned u = __float_as_uint(f);
    u += 0x7fffu + ((u >> 16) & 1u);
    return (unsigned short)(u >> 16);
}
__device__ inline unsigned bfr2(float lo, float hi) {  // pack 2 bf16 into dword
    return (unsigned)bfr(lo) | ((unsigned)bfr(hi) << 16);
}
__device__ inline float b2f(unsigned short u) {
    return __uint_as_float((unsigned)u << 16);
}

__device__ __forceinline__ void gl_lds16(const void* g, void* l) {
    __builtin_amdgcn_global_load_lds(
        (const __attribute__((address_space(1))) unsigned int*)g,
        (__attribute__((address_space(3))) unsigned int*)l, 16, 0, 0);
}

// cvt tile routine: TWO 64-k tiles of f32 [K][N] -> blocked-transposed bf16
// dst[((e*KBt+kb)*N + n)*64 + p*8 + i] = bf16(W[kb*64 + j*8 + i][n]), p = j ^ (n&7)
__device__ __forceinline__ void cvt_tile(
    const float* __restrict__ src, unsigned short* __restrict__ dst,
    int N, int KBt, int e, int kb0, int n0, void* smem, int tid)
{
    unsigned (*Ls)[32][65] = (unsigned (*)[32][65])smem;  // packed bf16 row-pairs
    const int c = (tid & 15) * 4, r2l = tid >> 4;
    #pragma unroll
    for (int t = 0; t < 2; t++) {
        const float* tsrc = src + (size_t)(kb0 + t) * 64 * N + n0;
        #pragma unroll
        for (int pass = 0; pass < 2; pass++) {
            int row2 = pass * 16 + r2l;
            float4 v0 = *(const float4*)(tsrc + (size_t)(2 * row2) * N + c);
            float4 v1 = *(const float4*)(tsrc + (size_t)(2 * row2 + 1) * N + c);
            uint4 o;
            o.x = bfr2(v0.x, v1.x); o.y = bfr2(v0.y, v1.y);
            o.z = bfr2(v0.z, v1.z); o.w = bfr2(v0.w, v1.w);
            *(uint4*)&Ls[t][row2][c] = o;
        }
    }
    __syncthreads();
    #pragma unroll
    for (int t = 0; t < 2; t++) {
        unsigned short* dbase = dst + ((size_t)(e * KBt + kb0 + t) * N + n0) * 64;
        #pragma unroll
        for (int half = 0; half < 2; half++) {
            int g = half * 256 + tid;
            int n = g >> 3, p = g & 7;
            int j4 = (p ^ (n & 7)) * 4;
            uint4 o;
            o.x = Ls[t][j4 + 0][n]; o.y = Ls[t][j4 + 1][n];
            o.z = Ls[t][j4 + 2][n]; o.w = Ls[t][j4 + 3][n];
            *(uint4*)(dbase + n * 64 + p * 8) = o;
        }
    }
}

// K1: blocks [0, GATE_BLKS): gating + x->bf16 (first, overlaps cvt).
// Blocks [GATE_BLKS, +CVT_TOT): W1/W2 conversion, 4 k-tiles per block.
// (r16-proven arrangement, best measured total)
__global__ __launch_bounds__(256) void k_gatecvt(
    const float* __restrict__ x, const float* __restrict__ gW,
    const float* __restrict__ gb, const float* __restrict__ bias,
    const float* __restrict__ W1, const float* __restrict__ sW1,
    const float* __restrict__ W2, const float* __restrict__ sW2,
    int* __restrict__ tokE, float* __restrict__ tokW,
    float* __restrict__ Ppart, int* __restrict__ Cpart,
    unsigned short* __restrict__ xb,
    unsigned short* __restrict__ W1b, unsigned short* __restrict__ W2b)
{
    __shared__ __align__(16) char smem[16896];
    const int tid = threadIdx.x;

    if (blockIdx.x >= GATE_BLKS) {
        int id = blockIdx.x - GATE_BLKS;
        if (id < CVT1_BLKS) {              // W1: K=DD, N=HH
            int n0 = (id % 12) * 64, kb0 = ((id / 12) % 4) * 4, e = id / 48;
            const float* src = (e < NE) ? (W1 + (size_t)e * DD * HH) : sW1;
            cvt_tile(src, W1b, HH, KB1, e, kb0, n0, smem, tid);
            __syncthreads();
            cvt_tile(src, W1b, HH, KB1, e, kb0 + 2, n0, smem, tid);
        } else {                           // W2: K=HH, N=DD
            id -= CVT1_BLKS;
            int n0 = (id % 16) * 64, kb0 = ((id / 16) % 3) * 4, e = id / 48;
            const float* src = (e < NE) ? (W2 + (size_t)e * HH * DD) : sW2;
            cvt_tile(src, W2b, DD, KB2, e, kb0, n0, smem, tid);
            __syncthreads();
            cvt_tile(src, W2b, DD, KB2, e, kb0 + 2, n0, smem, tid);
        }
        return;
    }

    // ---------------- gating path ----------------
    float (*xs)[DD] = (float (*)[DD])smem;                   // 16384 B
    float (*gv)[NE] = (float (*)[NE])(smem + 16384);         // 368 B
    float* ginvs    = (float*)(smem + 16768);                // 16 B
    int (*sel)[3]   = (int (*)[3])(smem + 16784);            // 48 B
    const int bid = blockIdx.x;
    const int t0 = bid * 4;
    {
        const float4* srcx = (const float4*)(x + (size_t)t0 * DD);
        float4* dstx = (float4*)&xs[0][0];
        #pragma unroll
        for (int i = 0; i < 4; i++) dstx[tid + 256 * i] = srcx[tid + 256 * i];
    }
    __syncthreads();
    {   // write bf16 copy of the 4 staged tokens
        const float* xf = &xs[0][0];
        unsigned short* xd = xb + (size_t)t0 * DD;
        #pragma unroll
        for (int it = 0; it < 4; it++) {
            int o = it * 1024 + tid * 4;
            ushort4 u = make_ushort4(bfr(xf[o]), bfr(xf[o + 1]), bfr(xf[o + 2]), bfr(xf[o + 3]));
            *(ushort4*)(xd + o) = u;
        }
    }
    const int w = tid >> 6, l = tid & 63;
    const int t = t0 + w;
    if (l < NE) {
        const float* gc = gW + l;
        const float* xw = xs[w];
        float s[4] = {0.f, 0.f, 0.f, 0.f};
        #pragma unroll 2
        for (int d0 = 0; d0 < DD; d0 += 16) {
            float g[16];
            #pragma unroll
            for (int j = 0; j < 16; j++) g[j] = gc[(d0 + j) * NE];
            #pragma unroll
            for (int j = 0; j < 16; j++) s[j & 3] = fmaf(xw[d0 + j], g[j], s[j & 3]);
        }
        float sv = (s[0] + s[1]) + (s[2] + s[3]) + gb[l];
        gv[w][l] = 1.f / (1.f + expf(-sv));
    }
    __syncthreads();
    if (l == 0) {
        unsigned chosen = 0;
        int be[3]; float bw[3];
        float gsum = 0.f;
        for (int e = 0; e < NE; e++) gsum += gv[w][e];
        #pragma unroll
        for (int k = 0; k < 3; k++) {
            float m = -1e30f; int mi = 0;
            for (int e = 0; e < NE; e++) {
                float kv = gv[w][e] + bias[e];
                if (!((chosen >> e) & 1u) && kv > m) { m = kv; mi = e; }
            }
            chosen |= 1u << mi;
            be[k] = mi; bw[k] = gv[w][mi];
        }
        float inv = 1.f / (bw[0] + bw[1] + bw[2]);
        #pragma unroll
        for (int k = 0; k < 3; k++) {
            tokE[t * 3 + k] = be[k];
            tokW[t * 3 + k] = bw[k] * inv;
            sel[w][k] = be[k];
        }
        ginvs[w] = 1.f / gsum;
    }
    __syncthreads();
    if (tid < NE) {   // per-block partials: NO global atomics
        float p = gv[0][tid] * ginvs[0] + gv[1][tid] * ginvs[1]
                + gv[2][tid] * ginvs[2] + gv[3][tid] * ginvs[3];
        Ppart[tid * 1024 + bid] = p;
        int c = 0;
        #pragma unroll
        for (int w2 = 0; w2 < 4; w2++)
            #pragma unroll
            for (int k = 0; k < 3; k++) c += (sel[w2][k] == tid);
        Cpart[tid * 1024 + bid] = c;
    }
}

// fused reduce + scan: single block, VECTORIZED partial reads (float4/int4,
// 4 independent vector loads per lane per expert -- avoids r10's scalar trap)
__global__ __launch_bounds__(256) void k_plan(
    const float* __restrict__ Ppart, const int* __restrict__ Cpart,
    int* __restrict__ offs, int* __restrict__ total,
    int* __restrict__ t2e, int* __restrict__ t2a,
    int* __restrict__ curs, float* __restrict__ outAux)
{
    __shared__ float sps[NE];
    __shared__ int scnt[NE];
    const int tid = threadIdx.x;
    for (int i = tid; i < NE * 16; i += 256) curs[i] = 0;   // replaces memset
    const int w = tid >> 6, lane = tid & 63;
    for (int e = w; e < NE; e += 4) {          // wave-per-expert round-robin
        const float4* pp = (const float4*)(Ppart + e * 1024);
        const int4*   cp = (const int4*)(Cpart + e * 1024);
        float s = 0.f; int c = 0;
        #pragma unroll
        for (int q = 0; q < 4; q++) {          // 1024 floats = 256 float4
            float4 v = pp[q * 64 + lane];
            int4   u = cp[q * 64 + lane];
            s += (v.x + v.y) + (v.z + v.w);
            c += (u.x + u.y) + (u.z + u.w);
        }
        #pragma unroll
        for (int off = 32; off >= 1; off >>= 1) {
            s += __shfl_down(s, off, 64);
            c += __shfl_down(c, off, 64);
        }
        if (lane == 0) { sps[e] = s; scnt[e] = c; }
    }
    __syncthreads();
    if (tid != 0) return;
    int off = 0, toff = 0;
    for (int e = 0; e < NG; e++) {
        int c = (e < NE) ? scnt[e] : TT;
        offs[e] = off;
        int nt = (c + BM - 1) / BM;
        for (int t = 0; t < nt; t++) {
            t2e[toff + t] = e;
            t2a[toff + t] = off + t * BM;
        }
        off += c; toff += nt;
    }
    offs[NG] = off;
    *total = toff;
    float aux = 0.f;
    for (int e = 0; e < NE; e++) {
        float P = sps[e] / (float)TT;
        float F = (float)NE * (float)scnt[e] / (float)(3 * TT);
        aux += P * F;
    }
    outAux[0] = aux;
    for (int e = 0; e < NE; e++) outAux[1 + e] = (float)scnt[e];
}

__global__ void k_scatter(const int* __restrict__ tokE, const float* __restrict__ tokW,
                          const int* __restrict__ offs, int* __restrict__ curs,
                          int* __restrict__ ltok, float* __restrict__ lw,
                          int* __restrict__ sidx)
{
    int t = blockIdx.x * 256 + threadIdx.x;
    if (t >= TT) return;
    #pragma unroll
    for (int k = 0; k < 3; k++) {
        int e = tokE[t * 3 + k];
        int pos = atomicAdd(&curs[e * 16], 1);   // 1 cache line per expert counter
        int idx = offs[e] + pos;
        ltok[idx] = t; lw[idx] = tokW[t * 3 + k];
        sidx[t * 3 + k] = idx;
    }
    ltok[3 * TT + t] = t;
    lw[3 * TT + t] = 1.f;
}

// grouped bf16-MFMA GEMM1 + fast GeLU; T3-minimum 2-phase (r8/r13 structure, best)
__global__ __launch_bounds__(256) void k_mm1(
    const unsigned short* __restrict__ xb, const unsigned short* __restrict__ W1b,
    const float* __restrict__ b1, const float* __restrict__ sb1,
    const int* __restrict__ t2e, const int* __restrict__ t2a,
    const int* __restrict__ offs, const int* __restrict__ total,
    const int* __restrict__ ltok, unsigned short* __restrict__ H)
{
    const int id = blockIdx.x;
    const int wg = (id & 7) * (NWG1 / 8) + (id >> 3);   // XCD-aware bijective swizzle
    const int ns = wg / MAXT;
    const int tb = wg % MAXT;
    if (tb >= *total) return;
    const int e = t2e[tb];
    const int a0 = t2a[tb];
    const int acount = min(offs[e + 1] - a0, BM);
    const float* bb = (e < NE) ? (b1 + e * HH) : sb1;
    const int nb = ns * BN;

    __shared__ unsigned short As[2][BM * BK];
    __shared__ unsigned short Bs[2][BN * BK];
    __shared__ int rows[BM];
    const int tid = threadIdx.x;
    if (tid < BM) rows[tid] = ltok[a0 + min(tid, acount - 1)];  // clamped gather
    __syncthreads();

    const int wid = tid >> 6, lane = tid & 63;
    const int wr = wid >> 1, wc = wid & 1;
    const int l15 = lane & 15, l4 = lane >> 4;

    float bv[4];
    #pragma unroll
    for (int n = 0; n < 4; n++) bv[n] = bb[nb + wc * 64 + n * 16 + l15];

    f32x4 acc[4][4];
    #pragma unroll
    for (int m = 0; m < 4; m++)
        #pragma unroll
        for (int n = 0; n < 4; n++) acc[m][n] = (f32x4){0.f, 0.f, 0.f, 0.f};

    const unsigned short* aSrc[4];
    int Goff[4];
    #pragma unroll
    for (int c = 0; c < 4; c++) {
        int G = (wid * 4 + c) * 64 + lane;
        int row = G >> 3, j = G & 7;
        aSrc[c] = xb + (size_t)rows[row] * DD + ((j ^ (row & 7)) << 3);
        Goff[c] = G * 8;
    }
    const unsigned short* wbase = W1b + ((size_t)e * KB1 * HH + nb) * 64;

    auto stage = [&](int buf, int kb) {   // 8 VMEM ops per thread
        #pragma unroll
        for (int c = 0; c < 4; c++)
            gl_lds16(aSrc[c] + kb * 64, &As[buf][Goff[c]]);
        const unsigned short* wb = wbase + (size_t)kb * (HH * 64);
        #pragma unroll
        for (int c = 0; c < 4; c++)
            gl_lds16(wb + Goff[c], &Bs[buf][Goff[c]]);
    };
    auto compute = [&](int buf) {
        #pragma unroll
        for (int kh = 0; kh < 2; kh++) {
            bf16x8 af[4], bf[4];
            #pragma unroll
            for (int f = 0; f < 4; f++) {
                int ar = wr * 64 + f * 16 + l15;
                int br = wc * 64 + f * 16 + l15;
                int pg = (kh << 2) + l4;
                af[f] = *(const bf16x8*)&As[buf][ar * 64 + ((pg ^ (ar & 7)) << 3)];
                bf[f] = *(const bf16x8*)&Bs[buf][br * 64 + ((pg ^ (br & 7)) << 3)];
            }
            #pragma unroll
            for (int m = 0; m < 4; m++)
                #pragma unroll
                for (int n = 0; n < 4; n++)
                    acc[m][n] = __builtin_amdgcn_mfma_f32_16x16x32_bf16(af[m], bf[n], acc[m][n], 0, 0, 0);
        }
    };

    stage(0, 0);
    WAIT_VM0();
    S_BARRIER();
    int cur = 0;
    #pragma unroll 1
    for (int kb = 0; kb < KB1; kb++) {
        if (kb + 1 < KB1) stage(cur ^ 1, kb + 1);   // issue next-tile loads FIRST
        __builtin_amdgcn_sched_barrier(0);          // pin issue order
        compute(cur);                               // MFMA hides the load latency
        if (kb + 1 < KB1) {
            WAIT_VM0();
            S_BARRIER();
            cur ^= 1;
        }
    }

    #pragma unroll
    for (int m = 0; m < 4; m++) {
        int rbase = wr * 64 + m * 16 + l4 * 4;
        #pragma unroll
        for (int n = 0; n < 4; n++) {
            int col = nb + wc * 64 + n * 16 + l15;
            #pragma unroll
            for (int i = 0; i < 4; i++) {
                int r = rbase + i;
                if (r < acount) {
                    float v = acc[m][n][i] + bv[n];
                    float u = v + 0.044715f * v * v * v;
                    float g = v / (1.f + __expf(-1.5957691216f * u));  // tanh-gelu
                    H[(size_t)(a0 + r) * HH + col] = bfr(g);
                }
            }
        }
    }
}

// grouped bf16-MFMA GEMM2; T3-minimum 2-phase (r8/r13 structure).
__global__ __launch_bounds__(256) void k_mm2(
    const unsigned short* __restrict__ H, const unsigned short* __restrict__ W2b,
    const float* __restrict__ b2, const float* __restrict__ sb2,
    const int* __restrict__ t2e, const int* __restrict__ t2a,
    const int* __restrict__ offs, const int* __restrict__ total,
    const int* __restrict__ ltok, const float* __restrict__ lw,
    unsigned short* __restrict__ yslot, float* __restrict__ out)
{
    const int id = blockIdx.x;
    const int wg = (id & 7) * (NWG2 / 8) + (id >> 3);
    const int ns = wg / MAXT;
    const int tb = wg % MAXT;
    if (tb >= *total) return;
    const int e = t2e[tb];
    const int a0 = t2a[tb];
    const int acount = min(offs[e + 1] - a0, BM);
    const float* bb = (e < NE) ? (b2 + e * DD) : sb2;
    const int nb = ns * BN;

    __shared__ unsigned short As[2][BM * BK];
    __shared__ unsigned short Bs[2][BN * BK];
    __shared__ int rows[BM];
    __shared__ float wts[BM];
    const int tid = threadIdx.x;
    if (tid < BM) {
        rows[tid] = (tid < acount) ? ltok[a0 + tid] : -1;
        wts[tid]  = (tid < acount) ? lw[a0 + tid] : 0.f;
    }
    __syncthreads();

    const int wid = tid >> 6, lane = tid & 63;
    const int wr = wid >> 1, wc = wid & 1;
    const int l15 = lane & 15, l4 = lane >> 4;

    float bv[4];
    #pragma unroll
    for (int n = 0; n < 4; n++) bv[n] = bb[nb + wc * 64 + n * 16 + l15];

    f32x4 acc[4][4];
    #pragma unroll
    for (int m = 0; m < 4; m++)
        #pragma unroll
        for (int n = 0; n < 4; n++) acc[m][n] = (f32x4){0.f, 0.f, 0.f, 0.f};

    const unsigned short* aSrc[4];
    int Goff[4];
    #pragma unroll
    for (int c = 0; c < 4; c++) {
        int G = (wid * 4 + c) * 64 + lane;
        int row = G >> 3, j = G & 7;
        aSrc[c] = H + (size_t)(a0 + row) * HH + ((j ^ (row & 7)) << 3);  // contiguous rows
        Goff[c] = G * 8;
    }
    const unsigned short* wbase = W2b + ((size_t)e * KB2 * DD + nb) * 64;

    auto stage = [&](int buf, int kb) {
        #pragma unroll
        for (int c = 0; c < 4; c++)
            gl_lds16(aSrc[c] + kb * 64, &As[buf][Goff[c]]);
        const unsigned short* wb = wbase + (size_t)kb * (DD * 64);
        #pragma unroll
        for (int c = 0; c < 4; c++)
            gl_lds16(wb + Goff[c], &Bs[buf][Goff[c]]);
    };
    auto compute = [&](int buf) {
        #pragma unroll
        for (int kh = 0; kh < 2; kh++) {
            bf16x8 af[4], bf[4];
            #pragma unroll
            for (int f = 0; f < 4; f++) {
                int ar = wr * 64 + f * 16 + l15;
                int br = wc * 64 + f * 16 + l15;
                int pg = (kh << 2) + l4;
                af[f] = *(const bf16x8*)&As[buf][ar * 64 + ((pg ^ (ar & 7)) << 3)];
                bf[f] = *(const bf16x8*)&Bs[buf][br * 64 + ((pg ^ (br & 7)) << 3)];
            }
            #pragma unroll
            for (int m = 0; m < 4; m++)
                #pragma unroll
                for (int n = 0; n < 4; n++)
                    acc[m][n] = __builtin_amdgcn_mfma_f32_16x16x32_bf16(af[m], bf[n], acc[m][n], 0, 0, 0);
        }
    };

    stage(0, 0);
    WAIT_VM0();
    S_BARRIER();
    int cur = 0;
    #pragma unroll 1
    for (int kb = 0; kb < KB2; kb++) {
        if (kb + 1 < KB2) stage(cur ^ 1, kb + 1);
        __builtin_amdgcn_sched_barrier(0);
        compute(cur);
        if (kb + 1 < KB2) {
            WAIT_VM0();
            S_BARRIER();
            cur ^= 1;
        }
    }

    if (e == NE) {
        // shared expert: every token, weight 1 -> plain f32 stores (covers whole out body)
        #pragma unroll
        for (int m = 0; m < 4; m++) {
            int rbase = wr * 64 + m * 16 + l4 * 4;
            #pragma unroll
            for (int n = 0; n < 4; n++) {
                int col = nb + wc * 64 + n * 16 + l15;
                #pragma unroll
                for (int i = 0; i < 4; i++) {
                    int r = rbase + i;
                    out[(size_t)rows[r] * DD + col] = acc[m][n][i] + bv[n];
                }
            }
        }
    } else {
        // expert tile: weighted bf16 partial into its slot row (no races, no atomics)
        #pragma unroll
        for (int m = 0; m < 4; m++) {
            int rbase = wr * 64 + m * 16 + l4 * 4;
            #pragma unroll
            for (int n = 0; n < 4; n++) {
                int col = nb + wc * 64 + n * 16 + l15;
                #pragma unroll
                for (int i = 0; i < 4; i++) {
                    int r = rbase + i;
                    if (r < acount)
                        yslot[(size_t)(a0 + r) * DD + col] = bfr(wts[r] * (acc[m][n][i] + bv[n]));
                }
            }
        }
    }
}

// out[t,:] += sum_k yslot[sidx[t,k],:]
__global__ __launch_bounds__(256) void k_combine(
    const unsigned short* __restrict__ yslot, const int* __restrict__ sidx,
    float* __restrict__ out)
{
    const int t = blockIdx.x;
    const int s0 = sidx[t * 3 + 0], s1 = sidx[t * 3 + 1], s2 = sidx[t * 3 + 2];
    const int d = threadIdx.x * 4;
    float* o = out + (size_t)t * DD + d;
    float4 v = *(float4*)o;
    ushort4 a = *(const ushort4*)(yslot + (size_t)s0 * DD + d);
    ushort4 b = *(const ushort4*)(yslot + (size_t)s1 * DD + d);
    ushort4 c = *(const ushort4*)(yslot + (size_t)s2 * DD + d);
    v.x += b2f(a.x) + b2f(b.x) + b2f(c.x);
    v.y += b2f(a.y) + b2f(b.y) + b2f(c.y);
    v.z += b2f(a.z) + b2f(b.z) + b2f(c.z);
    v.w += b2f(a.w) + b2f(b.w) + b2f(c.w);
    *(float4*)o = v;
}

extern "C" void kernel_launch(void* const* d_in, const int* in_sizes, int n_in,
                              void* d_out, int out_size, void* d_ws, size_t ws_size,
                              hipStream_t stream)
{
    const float* x    = (const float*)d_in[0];
    const float* gW   = (const float*)d_in[1];
    const float* gb   = (const float*)d_in[2];
    const float* bias = (const float*)d_in[3];
    const float* W1   = (const float*)d_in[4];
    const float* b1   = (const float*)d_in[5];
    const float* W2   = (const float*)d_in[6];
    const float* b2   = (const float*)d_in[7];
    const float* sW1  = (const float*)d_in[8];
    const float* sb1  = (const float*)d_in[9];
    const float* sW2  = (const float*)d_in[10];
    const float* sb2  = (const float*)d_in[11];
    float* out = (float*)d_out;
    float* wsf = (float*)d_ws;
    int*   wsi = (int*)d_ws;

    int*   curs   = wsi + WS_CURS;
    int*   offs   = wsi + WS_OFFS;
    int*   total  = wsi + WS_TOTAL;
    int*   t2e    = wsi + WS_T2E;
    int*   t2a    = wsi + WS_T2A;
    int*   tokE   = wsi + WS_TOKE;
    float* tokW   = wsf + WS_TOKW;
    int*   ltok   = wsi + WS_LTOK;
    float* lwt    = wsf + WS_LW;
    float* Ppart  = wsf + WS_PPART;
    int*   Cpart  = wsi + WS_CPART;
    int*   sidx   = wsi + WS_SIDX;
    unsigned short* xb  = (unsigned short*)((char*)d_ws + XB_OFF);
    unsigned short* Hb  = (unsigned short*)((char*)d_ws + H_OFF);
    unsigned short* W1b = (unsigned short*)((char*)d_ws + W1B_OFF);
    unsigned short* W2b = (unsigned short*)((char*)d_ws + W2B_OFF);
    unsigned short* yslot = W1b;   // reuse W1b region after k_mm1 is done

    k_gatecvt<<<GATE_BLKS + CVT_TOT, 256, 0, stream>>>(
        x, gW, gb, bias, W1, sW1, W2, sW2, tokE, tokW, Ppart, Cpart, xb, W1b, W2b);
    k_plan<<<1, 256, 0, stream>>>(Ppart, Cpart, offs, total, t2e, t2a, curs,
                                  out + (size_t)TT * DD);
    k_scatter<<<TT / 256, 256, 0, stream>>>(tokE, tokW, offs, curs, ltok, lwt, sidx);
    k_mm1<<<NWG1, 256, 0, stream>>>(xb, W1b, b1, sb1, t2e, t2a, offs, total, ltok, Hb);
    k_mm2<<<NWG2, 256, 0, stream>>>(Hb, W2b, b2, sb2, t2e, t2a, offs, total, ltok, lwt,
                                    yslot, out);
    k_combine<<<TT, 256, 0, stream>>>(yslot, sidx, out);
}